// Round 9
// baseline (986.535 us; speedup 1.0000x reference)
//
#include <hip/hip_runtime.h>
#include <math.h>

// ---------------------------------------------------------------------------
// SNAT3: 4-layer GAT GNN. N=50000, E=800000, HID=64, fp32.
// R9 dense structure: block=256thr=64 nodes; lane=node; wave wv owns features
// [16wv,16wv+16). Activations: per-lane float4 GLOBAL loads of the lane's own
// node row -> land in VGPRs by construction (global loads can't be sunk or
// rematerialized -- defeats the R6-R8 compiler fights: sink@52VGPR / spill@14MB).
// Waves 1-3 re-read the same 16KB of rows through L1. Weights: wave-uniform
// s_load from transposed wt[f][k] -> inner loops are pure v_fma v,v,s.
// LDS only for small cross-wave exchanges (pad-65 rows = 2-way banks).
// k_aggr / CSR build unchanged.
// ---------------------------------------------------------------------------

#define WT_EMB 0
#define WT_GAT 8192
#define WT_W0  24576
#define WT_W1  40960
#define WT_TOT 45056

__global__ void k_prep(const float* __restrict__ We, const float* __restrict__ Wg,
                       const float* __restrict__ W0, const float* __restrict__ W1,
                       float* __restrict__ wt, int* __restrict__ counts, int N) {
  int i = blockIdx.x * 256 + threadIdx.x;
  if (i < N) counts[i] = 0;
  if (i < 8192) {                       // W_embed [128][64] -> [64f][128k]
    int k = i >> 6, f = i & 63;
    wt[WT_EMB + f * 128 + k] = We[i];
  } else if (i < 24576) {               // W_gat [4][64][64] -> [4][64f][64k]
    int j = i - 8192, l = j >> 12, r = j & 4095;
    int k = r >> 6, f = r & 63;
    wt[WT_GAT + l * 4096 + f * 64 + k] = Wg[j];
  } else if (i < 40960) {               // W0 [256][64] -> [64f][256k]
    int j = i - 24576, k = j >> 6, f = j & 63;
    wt[WT_W0 + f * 256 + k] = W0[j];
  } else if (i < WT_TOT) {              // W1 [64][64] -> [64f][64k]
    int j = i - 40960, k = j >> 6, f = j & 63;
    wt[WT_W1 + f * 64 + k] = W1[j];
  }
}

__global__ void k_hist(const int* __restrict__ dst, int* __restrict__ counts, int E) {
  int e = blockIdx.x * blockDim.x + threadIdx.x;
  if (e < E) atomicAdd(&counts[dst[e]], 1);
}

__global__ __launch_bounds__(1024) void k_bsum(const int* __restrict__ counts,
                                               int* __restrict__ bsum, int n) {
  __shared__ int wsum[16];
  int tid = threadIdx.x, lane = tid & 63, wid = tid >> 6;
  int i = blockIdx.x * 1024 + tid;
  int v = (i < n) ? counts[i] : 0;
  #pragma unroll
  for (int off = 32; off; off >>= 1) v += __shfl_xor(v, off, 64);
  if (lane == 0) wsum[wid] = v;
  __syncthreads();
  if (wid == 0) {
    int w = (lane < 16) ? wsum[lane] : 0;
    #pragma unroll
    for (int off = 8; off; off >>= 1) w += __shfl_xor(w, off, 64);
    if (lane == 0) bsum[blockIdx.x] = w;
  }
}

__global__ __launch_bounds__(64) void k_bscan(const int* __restrict__ bsum,
                                              int* __restrict__ bofs,
                                              int* __restrict__ row_ptr,
                                              int nb, int n) {
  int lane = threadIdx.x;
  int carry = 0;
  for (int base = 0; base < nb; base += 64) {
    int idx = base + lane;
    int orig = (idx < nb) ? bsum[idx] : 0;
    int inc = orig;
    #pragma unroll
    for (int off = 1; off < 64; off <<= 1) {
      int t = __shfl_up(inc, off, 64);
      if (lane >= off) inc += t;
    }
    if (idx < nb) bofs[idx] = carry + inc - orig;
    carry += __shfl(inc, 63, 64);
  }
  if (lane == 0) row_ptr[n] = carry;
}

__global__ __launch_bounds__(1024) void k_scan3(const int* __restrict__ counts,
                                                const int* __restrict__ bofs,
                                                int* __restrict__ row_ptr,
                                                int* __restrict__ cursor, int n) {
  __shared__ int wsum[16];
  int tid = threadIdx.x, lane = tid & 63, wid = tid >> 6;
  int i = blockIdx.x * 1024 + tid;
  int v = (i < n) ? counts[i] : 0;
  int inc = v;
  #pragma unroll
  for (int off = 1; off < 64; off <<= 1) {
    int t = __shfl_up(inc, off, 64);
    if (lane >= off) inc += t;
  }
  if (lane == 63) wsum[wid] = inc;
  __syncthreads();
  if (wid == 0 && lane < 16) {
    int orig = wsum[lane];
    int w = orig;
    #pragma unroll
    for (int off = 1; off < 16; off <<= 1) {
      int t = __shfl_up(w, off, 64);
      if (lane >= off) w += t;
    }
    wsum[lane] = w - orig;
  }
  __syncthreads();
  int excl = bofs[blockIdx.x] + wsum[wid] + inc - v;
  if (i < n) { row_ptr[i] = excl; cursor[i] = excl; }
}

__global__ void k_scatter(const int* __restrict__ src, const int* __restrict__ dst,
                          int* __restrict__ cursor, int* __restrict__ csr_src, int E) {
  int e = blockIdx.x * blockDim.x + threadIdx.x;
  if (e < E) {
    int pos = atomicAdd(&cursor[dst[e]], 1);
    csr_src[pos] = src[e];
  }
}

// ---- fused: h = tanh(x@We); feat = h@Wg0; el/er.  lane=node ----
__global__ __launch_bounds__(256, 3) void k_embed_feat(
    const float* __restrict__ x, const float* __restrict__ wte,
    const float* __restrict__ wtg, const float* __restrict__ al,
    const float* __restrict__ ar, float* __restrict__ feat,
    float* __restrict__ el, float* __restrict__ er, int N) {
  __shared__ float sB[64 * 65];   // h exchange [node][f], pad65 -> 2-way banks
  __shared__ float sE[8 * 64];    // el/er partials [2][wave][lane]
  int tid = threadIdx.x, lane = tid & 63, wv = tid >> 6;
  int n = blockIdx.x * 64 + lane;
  int nn = min(n, N - 1);
  int f0 = wv * 16;
  const float* xp = x + (size_t)nn * 128;
  float acc[16];
  #pragma unroll
  for (int f = 0; f < 16; f++) acc[f] = 0.f;
  for (int kc = 0; kc < 8; kc++) {   // K=128 in chunks of 16 (acts in VGPRs)
    float4 v0 = *(const float4*)(xp + kc * 16 + 0);
    float4 v1 = *(const float4*)(xp + kc * 16 + 4);
    float4 v2 = *(const float4*)(xp + kc * 16 + 8);
    float4 v3 = *(const float4*)(xp + kc * 16 + 12);
    float a[16] = {v0.x, v0.y, v0.z, v0.w, v1.x, v1.y, v1.z, v1.w,
                   v2.x, v2.y, v2.z, v2.w, v3.x, v3.y, v3.z, v3.w};
    #pragma unroll
    for (int f = 0; f < 16; f++) {
      const float* wr = wte + (f0 + f) * 128 + kc * 16;  // uniform -> s_load
      #pragma unroll
      for (int k = 0; k < 16; k++) acc[f] = fmaf(a[k], wr[k], acc[f]);
    }
  }
  #pragma unroll
  for (int f = 0; f < 16; f++) sB[lane * 65 + f0 + f] = tanhf(acc[f]);
  __syncthreads();
  float a0[64];
  #pragma unroll
  for (int k = 0; k < 64; k++) a0[k] = sB[lane * 65 + k];
  float acc2[16];
  #pragma unroll
  for (int f = 0; f < 16; f++) acc2[f] = 0.f;
  #pragma unroll
  for (int f = 0; f < 16; f++) {
    const float* wr = wtg + (f0 + f) * 64;               // uniform -> s_load
    #pragma unroll
    for (int k = 0; k < 64; k++) acc2[f] = fmaf(a0[k], wr[k], acc2[f]);
  }
  float rl = 0.f, rr = 0.f;
  #pragma unroll
  for (int f = 0; f < 16; f++) {
    rl = fmaf(acc2[f], al[f0 + f], rl);
    rr = fmaf(acc2[f], ar[f0 + f], rr);
  }
  sE[wv * 64 + lane] = rl;
  sE[256 + wv * 64 + lane] = rr;
  {  // store this wave's 16-feature slice of the node row
    float* fp = feat + (size_t)nn * 64 + f0;
    *(float4*)(fp + 0)  = make_float4(acc2[0],  acc2[1],  acc2[2],  acc2[3]);
    *(float4*)(fp + 4)  = make_float4(acc2[4],  acc2[5],  acc2[6],  acc2[7]);
    *(float4*)(fp + 8)  = make_float4(acc2[8],  acc2[9],  acc2[10], acc2[11]);
    *(float4*)(fp + 12) = make_float4(acc2[12], acc2[13], acc2[14], acc2[15]);
  }
  __syncthreads();
  if (tid < 64) {
    int no = blockIdx.x * 64 + tid;
    if (no < N) {
      el[no] = (sE[tid] + sE[64 + tid]) + (sE[128 + tid] + sE[192 + tid]);
      er[no] = (sE[256 + tid] + sE[320 + tid]) + (sE[384 + tid] + sE[448 + tid]);
    }
  }
}

// ---- feat = hin @ Wg; el/er (layers 1..3). lane=node ----
__global__ __launch_bounds__(256, 3) void k_feat(const float* __restrict__ hin,
                                                 const float* __restrict__ wt,
                                                 const float* __restrict__ al,
                                                 const float* __restrict__ ar,
                                                 float* __restrict__ feat,
                                                 float* __restrict__ el,
                                                 float* __restrict__ er, int N) {
  __shared__ float sE[8 * 64];
  int tid = threadIdx.x, lane = tid & 63, wv = tid >> 6;
  int n = blockIdx.x * 64 + lane;
  int nn = min(n, N - 1);
  int f0 = wv * 16;
  const float* hp = hin + (size_t)nn * 64;
  float a[64];                       // acts from GLOBAL -> must stay in VGPRs
  #pragma unroll
  for (int c = 0; c < 16; c++) {
    float4 v = *(const float4*)(hp + c * 4);
    a[c * 4 + 0] = v.x; a[c * 4 + 1] = v.y; a[c * 4 + 2] = v.z; a[c * 4 + 3] = v.w;
  }
  float acc[16];
  #pragma unroll
  for (int f = 0; f < 16; f++) acc[f] = 0.f;
  #pragma unroll
  for (int f = 0; f < 16; f++) {
    const float* wr = wt + (f0 + f) * 64;   // uniform -> s_load
    #pragma unroll
    for (int k = 0; k < 64; k++) acc[f] = fmaf(a[k], wr[k], acc[f]);
  }
  float rl = 0.f, rr = 0.f;
  #pragma unroll
  for (int f = 0; f < 16; f++) {
    rl = fmaf(acc[f], al[f0 + f], rl);
    rr = fmaf(acc[f], ar[f0 + f], rr);
  }
  sE[wv * 64 + lane] = rl;
  sE[256 + wv * 64 + lane] = rr;
  {
    float* fp = feat + (size_t)nn * 64 + f0;
    *(float4*)(fp + 0)  = make_float4(acc[0],  acc[1],  acc[2],  acc[3]);
    *(float4*)(fp + 4)  = make_float4(acc[4],  acc[5],  acc[6],  acc[7]);
    *(float4*)(fp + 8)  = make_float4(acc[8],  acc[9],  acc[10], acc[11]);
    *(float4*)(fp + 12) = make_float4(acc[12], acc[13], acc[14], acc[15]);
  }
  __syncthreads();
  if (tid < 64) {
    int no = blockIdx.x * 64 + tid;
    if (no < N) {
      el[no] = (sE[tid] + sE[64 + tid]) + (sE[128 + tid] + sE[192 + tid]);
      er[no] = (sE[256 + tid] + sE[320 + tid]) + (sE[384 + tid] + sE[448 + tid]);
    }
  }
}

// ---- edge softmax + aggregate: one wave per dst node, lane = feature ----
__global__ __launch_bounds__(256) void k_aggr(const float* __restrict__ feat,
                                              const float* __restrict__ el,
                                              const float* __restrict__ er,
                                              const int* __restrict__ row_ptr,
                                              const int* __restrict__ csr_src,
                                              unsigned char* __restrict__ mask,
                                              int write_mask, int use_mask,
                                              float* __restrict__ hout, int N) {
  __shared__ __align__(16) int   su[4][64];
  __shared__ __align__(16) float spl[4][64];
  int wv = (int)((blockIdx.x * blockDim.x + threadIdx.x) >> 6);
  int wave = threadIdx.x >> 6, lane = threadIdx.x & 63;
  if (wv >= N) return;
  int beg = row_ptr[wv], end = row_ptr[wv + 1];
  int deg = end - beg;
  float erv = er[wv];
  float acc0 = 0.f, acc1 = 0.f, acc2 = 0.f, acc3 = 0.f;
  if (deg <= 64) {
    int k = beg + lane;
    bool have = (lane < deg);
    int u = have ? csr_src[k] : 0;
    float sc = -INFINITY;
    if (have) {
      float e0 = el[u] + erv;
      sc = (e0 >= 0.f) ? e0 : 0.2f * e0;
      if (use_mask && mask[k] == 0) sc = -1e9f;
    }
    float m = sc;
    #pragma unroll
    for (int off = 32; off; off >>= 1) m = fmaxf(m, __shfl_xor(m, off, 64));
    float pl = have ? expf(sc - m) : 0.f;
    float s = pl;
    #pragma unroll
    for (int off = 32; off; off >>= 1) s += __shfl_xor(s, off, 64);
    pl *= 1.0f / fmaxf(s, 1e-9f);
    if (write_mask && have) mask[k] = (pl >= 0.01f) ? 1 : 0;
    su[wave][lane] = u;
    spl[wave][lane] = pl;
    int dq = (deg + 3) >> 2;
    #pragma unroll 2
    for (int q = 0; q < dq; q++) {
      int4   uu = *(const int4*)&su[wave][q * 4];
      float4 pp = *(const float4*)&spl[wave][q * 4];
      acc0 = fmaf(pp.x, feat[(size_t)uu.x * 64 + lane], acc0);
      acc1 = fmaf(pp.y, feat[(size_t)uu.y * 64 + lane], acc1);
      acc2 = fmaf(pp.z, feat[(size_t)uu.z * 64 + lane], acc2);
      acc3 = fmaf(pp.w, feat[(size_t)uu.w * 64 + lane], acc3);
    }
  } else {
    float m = -INFINITY, s = 0.f;
    for (int base = beg; base < end; base += 64) {
      int k = base + lane;
      float sc = -INFINITY;
      if (k < end) {
        int u = csr_src[k];
        float e0 = el[u] + erv;
        sc = (e0 >= 0.f) ? e0 : 0.2f * e0;
        if (use_mask && mask[k] == 0) sc = -1e9f;
      }
      float cm = sc;
      #pragma unroll
      for (int off = 32; off; off >>= 1) cm = fmaxf(cm, __shfl_xor(cm, off, 64));
      float nm = fmaxf(m, cm);
      float t = (k < end) ? expf(sc - nm) : 0.f;
      #pragma unroll
      for (int off = 32; off; off >>= 1) t += __shfl_xor(t, off, 64);
      s = s * expf(m - nm) + t;
      m = nm;
    }
    float inv = 1.0f / fmaxf(s, 1e-9f);
    for (int base = beg; base < end; base += 64) {
      int k = base + lane;
      int u = 0;
      float pl = 0.f;
      if (k < end) {
        u = csr_src[k];
        float e0 = el[u] + erv;
        float sc = (e0 >= 0.f) ? e0 : 0.2f * e0;
        if (use_mask && mask[k] == 0) sc = -1e9f;
        pl = expf(sc - m) * inv;
        if (write_mask) mask[k] = (pl >= 0.01f) ? 1 : 0;
      }
      su[wave][lane] = u;
      spl[wave][lane] = pl;
      int cnt = min(64, end - base);
      int dq = (cnt + 3) >> 2;
      for (int q = 0; q < dq; q++) {
        int4   uu = *(const int4*)&su[wave][q * 4];
        float4 pp = *(const float4*)&spl[wave][q * 4];
        acc0 = fmaf(pp.x, feat[(size_t)uu.x * 64 + lane], acc0);
        acc1 = fmaf(pp.y, feat[(size_t)uu.y * 64 + lane], acc1);
        acc2 = fmaf(pp.z, feat[(size_t)uu.z * 64 + lane], acc2);
        acc3 = fmaf(pp.w, feat[(size_t)uu.w * 64 + lane], acc3);
      }
    }
  }
  float acc = (acc0 + acc1) + (acc2 + acc3);
  hout[(size_t)wv * 64 + lane] = (acc > 0.f) ? acc : expm1f(acc);
}

// ---- fused MLP head: lane=node; wave=16-feature chunk ----
__global__ __launch_bounds__(256, 3) void k_mlp(const float* __restrict__ o0,
                                                const float* __restrict__ o1,
                                                const float* __restrict__ o2,
                                                const float* __restrict__ o3,
                                                const float* __restrict__ wt0,
                                                const float* __restrict__ b0,
                                                const float* __restrict__ wt1,
                                                const float* __restrict__ b1,
                                                const float* __restrict__ W2,
                                                const float* __restrict__ b2,
                                                float* __restrict__ out, int N) {
  __shared__ float sB[64 * 65];   // layer-0 output exchange
  __shared__ float sR[4 * 64];    // layer-2 partials
  int tid = threadIdx.x, lane = tid & 63, wv = tid >> 6;
  int n = blockIdx.x * 64 + lane;
  int nn = min(n, N - 1);
  int f0 = wv * 16;
  float acc[16];
  #pragma unroll
  for (int f = 0; f < 16; f++) acc[f] = b0[f0 + f];
  const float* segs[4] = {o0, o1, o2, o3};
  for (int sg = 0; sg < 4; sg++) {
    const float* sp = segs[sg] + (size_t)nn * 64;
    float a[64];                     // acts from GLOBAL -> stay in VGPRs
    #pragma unroll
    for (int c = 0; c < 16; c++) {
      float4 v = *(const float4*)(sp + c * 4);
      a[c * 4 + 0] = v.x; a[c * 4 + 1] = v.y; a[c * 4 + 2] = v.z; a[c * 4 + 3] = v.w;
    }
    #pragma unroll
    for (int f = 0; f < 16; f++) {
      const float* wr = wt0 + (f0 + f) * 256 + sg * 64;   // uniform -> s_load
      #pragma unroll
      for (int k = 0; k < 64; k++) acc[f] = fmaf(a[k], wr[k], acc[f]);
    }
  }
  #pragma unroll
  for (int f = 0; f < 16; f++)
    sB[lane * 65 + f0 + f] = (acc[f] > 0.f) ? acc[f] : 0.f;   // relu
  __syncthreads();
  float a0[64];
  #pragma unroll
  for (int k = 0; k < 64; k++) a0[k] = sB[lane * 65 + k];
  float rp = 0.f;
  #pragma unroll
  for (int f = 0; f < 16; f++) {
    float a1 = b1[f0 + f];
    const float* wr = wt1 + (f0 + f) * 64;                // uniform -> s_load
    #pragma unroll
    for (int k = 0; k < 64; k++) a1 = fmaf(a0[k], wr[k], a1);
    float t = (a1 > 0.f) ? a1 : 0.f;
    rp = fmaf(t, W2[f0 + f], rp);
  }
  sR[wv * 64 + lane] = rp;
  __syncthreads();
  if (tid < 64) {
    int no = blockIdx.x * 64 + tid;
    if (no < N) {
      float o = (sR[tid] + sR[64 + tid]) + (sR[128 + tid] + sR[192 + tid]) + b2[0];
      out[no] = (o > 0.f) ? o : 0.f;
    }
  }
}

extern "C" void kernel_launch(void* const* d_in, const int* in_sizes, int n_in,
                              void* d_out, int out_size, void* d_ws, size_t ws_size,
                              hipStream_t stream) {
  const float* x       = (const float*)d_in[0];
  const int*   esrc    = (const int*)d_in[1];
  const int*   edst    = (const int*)d_in[2];
  const float* W_embed = (const float*)d_in[3];
  const float* W_gat   = (const float*)d_in[4];
  const float* a_l     = (const float*)d_in[5];
  const float* a_r     = (const float*)d_in[6];
  const float* W0      = (const float*)d_in[7];
  const float* b0      = (const float*)d_in[8];
  const float* W1      = (const float*)d_in[9];
  const float* b1      = (const float*)d_in[10];
  const float* W2      = (const float*)d_in[11];
  const float* b2      = (const float*)d_in[12];
  float* out = (float*)d_out;
  const int N = in_sizes[0] / 128;
  const int E = in_sizes[1];

  char* p = (char*)d_ws;
  auto alloc = [&](size_t bytes) -> char* {
    char* r = p;
    p += (bytes + 255) & ~(size_t)255;
    return r;
  };
  float* out0 = (float*)alloc((size_t)N * 64 * 4);
  float* out1 = (float*)alloc((size_t)N * 64 * 4);
  float* out2 = (float*)alloc((size_t)N * 64 * 4);
  float* out3 = (float*)alloc((size_t)N * 64 * 4);
  float* feat = (float*)alloc((size_t)N * 64 * 4);
  float* el   = (float*)alloc((size_t)N * 4);
  float* er   = (float*)alloc((size_t)N * 4);
  int* counts  = (int*)alloc((size_t)N * 4);
  int* row_ptr = (int*)alloc((size_t)(N + 1) * 4);
  int* cursor  = (int*)alloc((size_t)N * 4);
  int* csr_src = (int*)alloc((size_t)E * 4);
  unsigned char* mask = (unsigned char*)alloc((size_t)E);
  int nb = (N + 1023) / 1024;
  int* bsum = (int*)alloc((size_t)nb * 4);
  int* bofs = (int*)alloc((size_t)nb * 4);
  float* wt = (float*)alloc((size_t)WT_TOT * 4);

  // --- prep: zero counts + transpose all weight matrices ---
  int prep_n = (N > WT_TOT) ? N : WT_TOT;
  k_prep<<<(prep_n + 255) / 256, 256, 0, stream>>>(W_embed, W_gat, W0, W1,
                                                   wt, counts, N);

  // --- CSR build (dst-sorted) ---
  k_hist<<<(E + 255) / 256, 256, 0, stream>>>(edst, counts, E);
  k_bsum<<<nb, 1024, 0, stream>>>(counts, bsum, N);
  k_bscan<<<1, 64, 0, stream>>>(bsum, bofs, row_ptr, nb, N);
  k_scan3<<<nb, 1024, 0, stream>>>(counts, bofs, row_ptr, cursor, N);
  k_scatter<<<(E + 255) / 256, 256, 0, stream>>>(esrc, edst, cursor, csr_src, E);

  // --- dense grid: 64 nodes per 256-thread block ---
  int dgb = (N + 63) / 64;

  // --- layer 0: fused embed + feat ---
  k_embed_feat<<<dgb, 256, 0, stream>>>(x, wt + WT_EMB, wt + WT_GAT,
                                        a_l, a_r, feat, el, er, N);
  float* outs[4] = {out0, out1, out2, out3};
  k_aggr<<<(N + 3) / 4, 256, 0, stream>>>(feat, el, er, row_ptr, csr_src, mask,
                                          1, 0, out0, N);

  // --- layers 1..3 ---
  for (int l = 1; l < 4; l++) {
    k_feat<<<dgb, 256, 0, stream>>>(outs[l - 1], wt + WT_GAT + (size_t)l * 4096,
                                    a_l + (size_t)l * 64, a_r + (size_t)l * 64,
                                    feat, el, er, N);
    k_aggr<<<(N + 3) / 4, 256, 0, stream>>>(feat, el, er, row_ptr, csr_src, mask,
                                            0, 1, outs[l], N);
  }

  // --- MLP head ---
  k_mlp<<<dgb, 256, 0, stream>>>(out0, out1, out2, out3, wt + WT_W0, b0,
                                 wt + WT_W1, b1, W2, b2, out, N);
}

// Round 10
// 739.510 us; speedup vs baseline: 1.3340x; 1.3340x over previous
//
#include <hip/hip_runtime.h>
#include <math.h>

// ---------------------------------------------------------------------------
// SNAT3: 4-layer GAT GNN. N=50000, E=800000, HID=64, fp32.
// R10 dense structure = R6 grid x R5 inner loop:
//   block=256thr=64 nodes; lane=node; wave wv owns features [16wv,16wv+16).
//   K processed in CHUNKS OF 16: 4x float4 global loads -> a[16] -> 16x16 FMA
//   block with weights from wave-uniform s_load (transposed wt[f][k]).
//   a[16] chunks keep live ranges small: the R5-verified codegen (88 VGPR,
//   no spill). R8 junk-fence -> spill-by-LDS-alias; R9 a[64]-from-global ->
//   400MB scratch spill. Never hold 64 floats live per lane on this compiler.
// LDS only for small exchanges (h in embed, layer0->1 in mlp, el/er, pad-65).
// ---------------------------------------------------------------------------

#define WT_EMB 0
#define WT_GAT 8192
#define WT_W0  24576
#define WT_W1  40960
#define WT_TOT 45056

__global__ void k_prep(const float* __restrict__ We, const float* __restrict__ Wg,
                       const float* __restrict__ W0, const float* __restrict__ W1,
                       float* __restrict__ wt, int* __restrict__ counts, int N) {
  int i = blockIdx.x * 256 + threadIdx.x;
  if (i < N) counts[i] = 0;
  if (i < 8192) {                       // W_embed [128][64] -> [64f][128k]
    int k = i >> 6, f = i & 63;
    wt[WT_EMB + f * 128 + k] = We[i];
  } else if (i < 24576) {               // W_gat [4][64][64] -> [4][64f][64k]
    int j = i - 8192, l = j >> 12, r = j & 4095;
    int k = r >> 6, f = r & 63;
    wt[WT_GAT + l * 4096 + f * 64 + k] = Wg[j];
  } else if (i < 40960) {               // W0 [256][64] -> [64f][256k]
    int j = i - 24576, k = j >> 6, f = j & 63;
    wt[WT_W0 + f * 256 + k] = W0[j];
  } else if (i < WT_TOT) {              // W1 [64][64] -> [64f][64k]
    int j = i - 40960, k = j >> 6, f = j & 63;
    wt[WT_W1 + f * 64 + k] = W1[j];
  }
}

__global__ void k_hist(const int* __restrict__ dst, int* __restrict__ counts, int E) {
  int e = blockIdx.x * blockDim.x + threadIdx.x;
  if (e < E) atomicAdd(&counts[dst[e]], 1);
}

__global__ __launch_bounds__(1024) void k_bsum(const int* __restrict__ counts,
                                               int* __restrict__ bsum, int n) {
  __shared__ int wsum[16];
  int tid = threadIdx.x, lane = tid & 63, wid = tid >> 6;
  int i = blockIdx.x * 1024 + tid;
  int v = (i < n) ? counts[i] : 0;
  #pragma unroll
  for (int off = 32; off; off >>= 1) v += __shfl_xor(v, off, 64);
  if (lane == 0) wsum[wid] = v;
  __syncthreads();
  if (wid == 0) {
    int w = (lane < 16) ? wsum[lane] : 0;
    #pragma unroll
    for (int off = 8; off; off >>= 1) w += __shfl_xor(w, off, 64);
    if (lane == 0) bsum[blockIdx.x] = w;
  }
}

__global__ __launch_bounds__(64) void k_bscan(const int* __restrict__ bsum,
                                              int* __restrict__ bofs,
                                              int* __restrict__ row_ptr,
                                              int nb, int n) {
  int lane = threadIdx.x;
  int carry = 0;
  for (int base = 0; base < nb; base += 64) {
    int idx = base + lane;
    int orig = (idx < nb) ? bsum[idx] : 0;
    int inc = orig;
    #pragma unroll
    for (int off = 1; off < 64; off <<= 1) {
      int t = __shfl_up(inc, off, 64);
      if (lane >= off) inc += t;
    }
    if (idx < nb) bofs[idx] = carry + inc - orig;
    carry += __shfl(inc, 63, 64);
  }
  if (lane == 0) row_ptr[n] = carry;
}

__global__ __launch_bounds__(1024) void k_scan3(const int* __restrict__ counts,
                                                const int* __restrict__ bofs,
                                                int* __restrict__ row_ptr,
                                                int* __restrict__ cursor, int n) {
  __shared__ int wsum[16];
  int tid = threadIdx.x, lane = tid & 63, wid = tid >> 6;
  int i = blockIdx.x * 1024 + tid;
  int v = (i < n) ? counts[i] : 0;
  int inc = v;
  #pragma unroll
  for (int off = 1; off < 64; off <<= 1) {
    int t = __shfl_up(inc, off, 64);
    if (lane >= off) inc += t;
  }
  if (lane == 63) wsum[wid] = inc;
  __syncthreads();
  if (wid == 0 && lane < 16) {
    int orig = wsum[lane];
    int w = orig;
    #pragma unroll
    for (int off = 1; off < 16; off <<= 1) {
      int t = __shfl_up(w, off, 64);
      if (lane >= off) w += t;
    }
    wsum[lane] = w - orig;
  }
  __syncthreads();
  int excl = bofs[blockIdx.x] + wsum[wid] + inc - v;
  if (i < n) { row_ptr[i] = excl; cursor[i] = excl; }
}

__global__ void k_scatter(const int* __restrict__ src, const int* __restrict__ dst,
                          int* __restrict__ cursor, int* __restrict__ csr_src, int E) {
  int e = blockIdx.x * blockDim.x + threadIdx.x;
  if (e < E) {
    int pos = atomicAdd(&cursor[dst[e]], 1);
    csr_src[pos] = src[e];
  }
}

// ---- fused: h = tanh(x@We); feat = h@Wg0; el/er.  lane=node ----
__global__ __launch_bounds__(256) void k_embed_feat(
    const float* __restrict__ x, const float* __restrict__ wte,
    const float* __restrict__ wtg, const float* __restrict__ al,
    const float* __restrict__ ar, float* __restrict__ feat,
    float* __restrict__ el, float* __restrict__ er, int N) {
  __shared__ float sB[64 * 65];   // h exchange [node][f], pad65 -> 2-way banks
  __shared__ float sE[8 * 64];    // el/er partials
  int tid = threadIdx.x, lane = tid & 63, wv = tid >> 6;
  int n = blockIdx.x * 64 + lane;
  int nn = min(n, N - 1);
  int f0 = wv * 16;
  const float* xp = x + (size_t)nn * 128;
  float acc[16];
  #pragma unroll
  for (int f = 0; f < 16; f++) acc[f] = 0.f;
  for (int kc = 0; kc < 8; kc++) {           // K=128, chunks of 16
    float4 v0 = *(const float4*)(xp + kc * 16 + 0);
    float4 v1 = *(const float4*)(xp + kc * 16 + 4);
    float4 v2 = *(const float4*)(xp + kc * 16 + 8);
    float4 v3 = *(const float4*)(xp + kc * 16 + 12);
    float a[16] = {v0.x, v0.y, v0.z, v0.w, v1.x, v1.y, v1.z, v1.w,
                   v2.x, v2.y, v2.z, v2.w, v3.x, v3.y, v3.z, v3.w};
    #pragma unroll
    for (int f = 0; f < 16; f++) {
      const float* wr = wte + (f0 + f) * 128 + kc * 16;  // uniform -> s_load
      #pragma unroll
      for (int k = 0; k < 16; k++) acc[f] = fmaf(a[k], wr[k], acc[f]);
    }
  }
  #pragma unroll
  for (int f = 0; f < 16; f++) sB[lane * 65 + f0 + f] = tanhf(acc[f]);
  __syncthreads();
  float acc2[16];
  #pragma unroll
  for (int f = 0; f < 16; f++) acc2[f] = 0.f;
  for (int kc = 0; kc < 4; kc++) {           // h from LDS, chunks of 16
    float a[16];
    #pragma unroll
    for (int k = 0; k < 16; k++) a[k] = sB[lane * 65 + kc * 16 + k];
    #pragma unroll
    for (int f = 0; f < 16; f++) {
      const float* wr = wtg + (f0 + f) * 64 + kc * 16;   // uniform -> s_load
      #pragma unroll
      for (int k = 0; k < 16; k++) acc2[f] = fmaf(a[k], wr[k], acc2[f]);
    }
  }
  float rl = 0.f, rr = 0.f;
  #pragma unroll
  for (int f = 0; f < 16; f++) {
    rl = fmaf(acc2[f], al[f0 + f], rl);
    rr = fmaf(acc2[f], ar[f0 + f], rr);
  }
  sE[wv * 64 + lane] = rl;
  sE[256 + wv * 64 + lane] = rr;
  {  // store this wave's 16-feature slice of the node row
    float* fp = feat + (size_t)nn * 64 + f0;
    *(float4*)(fp + 0)  = make_float4(acc2[0],  acc2[1],  acc2[2],  acc2[3]);
    *(float4*)(fp + 4)  = make_float4(acc2[4],  acc2[5],  acc2[6],  acc2[7]);
    *(float4*)(fp + 8)  = make_float4(acc2[8],  acc2[9],  acc2[10], acc2[11]);
    *(float4*)(fp + 12) = make_float4(acc2[12], acc2[13], acc2[14], acc2[15]);
  }
  __syncthreads();
  if (tid < 64) {
    int no = blockIdx.x * 64 + tid;
    if (no < N) {
      el[no] = (sE[tid] + sE[64 + tid]) + (sE[128 + tid] + sE[192 + tid]);
      er[no] = (sE[256 + tid] + sE[320 + tid]) + (sE[384 + tid] + sE[448 + tid]);
    }
  }
}

// ---- feat = hin @ Wg; el/er (layers 1..3). lane=node ----
__global__ __launch_bounds__(256) void k_feat(const float* __restrict__ hin,
                                              const float* __restrict__ wt,
                                              const float* __restrict__ al,
                                              const float* __restrict__ ar,
                                              float* __restrict__ feat,
                                              float* __restrict__ el,
                                              float* __restrict__ er, int N) {
  __shared__ float sE[8 * 64];
  int tid = threadIdx.x, lane = tid & 63, wv = tid >> 6;
  int n = blockIdx.x * 64 + lane;
  int nn = min(n, N - 1);
  int f0 = wv * 16;
  const float* hp = hin + (size_t)nn * 64;
  float acc[16];
  #pragma unroll
  for (int f = 0; f < 16; f++) acc[f] = 0.f;
  for (int kc = 0; kc < 4; kc++) {           // K=64, chunks of 16
    float4 v0 = *(const float4*)(hp + kc * 16 + 0);
    float4 v1 = *(const float4*)(hp + kc * 16 + 4);
    float4 v2 = *(const float4*)(hp + kc * 16 + 8);
    float4 v3 = *(const float4*)(hp + kc * 16 + 12);
    float a[16] = {v0.x, v0.y, v0.z, v0.w, v1.x, v1.y, v1.z, v1.w,
                   v2.x, v2.y, v2.z, v2.w, v3.x, v3.y, v3.z, v3.w};
    #pragma unroll
    for (int f = 0; f < 16; f++) {
      const float* wr = wt + (f0 + f) * 64 + kc * 16;    // uniform -> s_load
      #pragma unroll
      for (int k = 0; k < 16; k++) acc[f] = fmaf(a[k], wr[k], acc[f]);
    }
  }
  float rl = 0.f, rr = 0.f;
  #pragma unroll
  for (int f = 0; f < 16; f++) {
    rl = fmaf(acc[f], al[f0 + f], rl);
    rr = fmaf(acc[f], ar[f0 + f], rr);
  }
  sE[wv * 64 + lane] = rl;
  sE[256 + wv * 64 + lane] = rr;
  {
    float* fp = feat + (size_t)nn * 64 + f0;
    *(float4*)(fp + 0)  = make_float4(acc[0],  acc[1],  acc[2],  acc[3]);
    *(float4*)(fp + 4)  = make_float4(acc[4],  acc[5],  acc[6],  acc[7]);
    *(float4*)(fp + 8)  = make_float4(acc[8],  acc[9],  acc[10], acc[11]);
    *(float4*)(fp + 12) = make_float4(acc[12], acc[13], acc[14], acc[15]);
  }
  __syncthreads();
  if (tid < 64) {
    int no = blockIdx.x * 64 + tid;
    if (no < N) {
      el[no] = (sE[tid] + sE[64 + tid]) + (sE[128 + tid] + sE[192 + tid]);
      er[no] = (sE[256 + tid] + sE[320 + tid]) + (sE[384 + tid] + sE[448 + tid]);
    }
  }
}

// ---- edge softmax + aggregate: one wave per dst node, lane = feature ----
__global__ __launch_bounds__(256) void k_aggr(const float* __restrict__ feat,
                                              const float* __restrict__ el,
                                              const float* __restrict__ er,
                                              const int* __restrict__ row_ptr,
                                              const int* __restrict__ csr_src,
                                              unsigned char* __restrict__ mask,
                                              int write_mask, int use_mask,
                                              float* __restrict__ hout, int N) {
  __shared__ __align__(16) int   su[4][64];
  __shared__ __align__(16) float spl[4][64];
  int wv = (int)((blockIdx.x * blockDim.x + threadIdx.x) >> 6);
  int wave = threadIdx.x >> 6, lane = threadIdx.x & 63;
  if (wv >= N) return;
  int beg = row_ptr[wv], end = row_ptr[wv + 1];
  int deg = end - beg;
  float erv = er[wv];
  float acc0 = 0.f, acc1 = 0.f, acc2 = 0.f, acc3 = 0.f;
  if (deg <= 64) {
    int k = beg + lane;
    bool have = (lane < deg);
    int u = have ? csr_src[k] : 0;
    float sc = -INFINITY;
    if (have) {
      float e0 = el[u] + erv;
      sc = (e0 >= 0.f) ? e0 : 0.2f * e0;
      if (use_mask && mask[k] == 0) sc = -1e9f;
    }
    float m = sc;
    #pragma unroll
    for (int off = 32; off; off >>= 1) m = fmaxf(m, __shfl_xor(m, off, 64));
    float pl = have ? expf(sc - m) : 0.f;
    float s = pl;
    #pragma unroll
    for (int off = 32; off; off >>= 1) s += __shfl_xor(s, off, 64);
    pl *= 1.0f / fmaxf(s, 1e-9f);
    if (write_mask && have) mask[k] = (pl >= 0.01f) ? 1 : 0;
    su[wave][lane] = u;
    spl[wave][lane] = pl;
    int dq = (deg + 3) >> 2;
    #pragma unroll 2
    for (int q = 0; q < dq; q++) {
      int4   uu = *(const int4*)&su[wave][q * 4];
      float4 pp = *(const float4*)&spl[wave][q * 4];
      acc0 = fmaf(pp.x, feat[(size_t)uu.x * 64 + lane], acc0);
      acc1 = fmaf(pp.y, feat[(size_t)uu.y * 64 + lane], acc1);
      acc2 = fmaf(pp.z, feat[(size_t)uu.z * 64 + lane], acc2);
      acc3 = fmaf(pp.w, feat[(size_t)uu.w * 64 + lane], acc3);
    }
  } else {
    float m = -INFINITY, s = 0.f;
    for (int base = beg; base < end; base += 64) {
      int k = base + lane;
      float sc = -INFINITY;
      if (k < end) {
        int u = csr_src[k];
        float e0 = el[u] + erv;
        sc = (e0 >= 0.f) ? e0 : 0.2f * e0;
        if (use_mask && mask[k] == 0) sc = -1e9f;
      }
      float cm = sc;
      #pragma unroll
      for (int off = 32; off; off >>= 1) cm = fmaxf(cm, __shfl_xor(cm, off, 64));
      float nm = fmaxf(m, cm);
      float t = (k < end) ? expf(sc - nm) : 0.f;
      #pragma unroll
      for (int off = 32; off; off >>= 1) t += __shfl_xor(t, off, 64);
      s = s * expf(m - nm) + t;
      m = nm;
    }
    float inv = 1.0f / fmaxf(s, 1e-9f);
    for (int base = beg; base < end; base += 64) {
      int k = base + lane;
      int u = 0;
      float pl = 0.f;
      if (k < end) {
        u = csr_src[k];
        float e0 = el[u] + erv;
        float sc = (e0 >= 0.f) ? e0 : 0.2f * e0;
        if (use_mask && mask[k] == 0) sc = -1e9f;
        pl = expf(sc - m) * inv;
        if (write_mask) mask[k] = (pl >= 0.01f) ? 1 : 0;
      }
      su[wave][lane] = u;
      spl[wave][lane] = pl;
      int cnt = min(64, end - base);
      int dq = (cnt + 3) >> 2;
      for (int q = 0; q < dq; q++) {
        int4   uu = *(const int4*)&su[wave][q * 4];
        float4 pp = *(const float4*)&spl[wave][q * 4];
        acc0 = fmaf(pp.x, feat[(size_t)uu.x * 64 + lane], acc0);
        acc1 = fmaf(pp.y, feat[(size_t)uu.y * 64 + lane], acc1);
        acc2 = fmaf(pp.z, feat[(size_t)uu.z * 64 + lane], acc2);
        acc3 = fmaf(pp.w, feat[(size_t)uu.w * 64 + lane], acc3);
      }
    }
  }
  float acc = (acc0 + acc1) + (acc2 + acc3);
  hout[(size_t)wv * 64 + lane] = (acc > 0.f) ? acc : expm1f(acc);
}

// ---- fused MLP head: lane=node; wave=16-feature chunk; chunked K ----
__global__ __launch_bounds__(256) void k_mlp(const float* __restrict__ o0,
                                             const float* __restrict__ o1,
                                             const float* __restrict__ o2,
                                             const float* __restrict__ o3,
                                             const float* __restrict__ wt0,
                                             const float* __restrict__ b0,
                                             const float* __restrict__ wt1,
                                             const float* __restrict__ b1,
                                             const float* __restrict__ W2,
                                             const float* __restrict__ b2,
                                             float* __restrict__ out, int N) {
  __shared__ float sB[64 * 65];   // layer-0 output exchange
  __shared__ float sR[4 * 64];    // layer-2 partials
  int tid = threadIdx.x, lane = tid & 63, wv = tid >> 6;
  int n = blockIdx.x * 64 + lane;
  int nn = min(n, N - 1);
  int f0 = wv * 16;
  float acc[16];
  #pragma unroll
  for (int f = 0; f < 16; f++) acc[f] = b0[f0 + f];
  const float* segs[4] = {o0, o1, o2, o3};
  for (int sg = 0; sg < 4; sg++) {
    const float* sp = segs[sg] + (size_t)nn * 64;
    for (int kc = 0; kc < 4; kc++) {         // 16-k chunks, a[16] live max
      float4 v0 = *(const float4*)(sp + kc * 16 + 0);
      float4 v1 = *(const float4*)(sp + kc * 16 + 4);
      float4 v2 = *(const float4*)(sp + kc * 16 + 8);
      float4 v3 = *(const float4*)(sp + kc * 16 + 12);
      float a[16] = {v0.x, v0.y, v0.z, v0.w, v1.x, v1.y, v1.z, v1.w,
                     v2.x, v2.y, v2.z, v2.w, v3.x, v3.y, v3.z, v3.w};
      #pragma unroll
      for (int f = 0; f < 16; f++) {
        const float* wr = wt0 + (f0 + f) * 256 + sg * 64 + kc * 16;  // s_load
        #pragma unroll
        for (int k = 0; k < 16; k++) acc[f] = fmaf(a[k], wr[k], acc[f]);
      }
    }
  }
  #pragma unroll
  for (int f = 0; f < 16; f++)
    sB[lane * 65 + f0 + f] = (acc[f] > 0.f) ? acc[f] : 0.f;   // relu
  __syncthreads();
  float a1[16];
  #pragma unroll
  for (int f = 0; f < 16; f++) a1[f] = b1[f0 + f];
  for (int kc = 0; kc < 4; kc++) {           // layer-1 acts from LDS, chunked
    float a[16];
    #pragma unroll
    for (int k = 0; k < 16; k++) a[k] = sB[lane * 65 + kc * 16 + k];
    #pragma unroll
    for (int f = 0; f < 16; f++) {
      const float* wr = wt1 + (f0 + f) * 64 + kc * 16;     // uniform -> s_load
      #pragma unroll
      for (int k = 0; k < 16; k++) a1[f] = fmaf(a[k], wr[k], a1[f]);
    }
  }
  float rp = 0.f;
  #pragma unroll
  for (int f = 0; f < 16; f++) {
    float t = (a1[f] > 0.f) ? a1[f] : 0.f;
    rp = fmaf(t, W2[f0 + f], rp);
  }
  sR[wv * 64 + lane] = rp;
  __syncthreads();
  if (tid < 64) {
    int no = blockIdx.x * 64 + tid;
    if (no < N) {
      float o = (sR[tid] + sR[64 + tid]) + (sR[128 + tid] + sR[192 + tid]) + b2[0];
      out[no] = (o > 0.f) ? o : 0.f;
    }
  }
}

extern "C" void kernel_launch(void* const* d_in, const int* in_sizes, int n_in,
                              void* d_out, int out_size, void* d_ws, size_t ws_size,
                              hipStream_t stream) {
  const float* x       = (const float*)d_in[0];
  const int*   esrc    = (const int*)d_in[1];
  const int*   edst    = (const int*)d_in[2];
  const float* W_embed = (const float*)d_in[3];
  const float* W_gat   = (const float*)d_in[4];
  const float* a_l     = (const float*)d_in[5];
  const float* a_r     = (const float*)d_in[6];
  const float* W0      = (const float*)d_in[7];
  const float* b0      = (const float*)d_in[8];
  const float* W1      = (const float*)d_in[9];
  const float* b1      = (const float*)d_in[10];
  const float* W2      = (const float*)d_in[11];
  const float* b2      = (const float*)d_in[12];
  float* out = (float*)d_out;
  const int N = in_sizes[0] / 128;
  const int E = in_sizes[1];

  char* p = (char*)d_ws;
  auto alloc = [&](size_t bytes) -> char* {
    char* r = p;
    p += (bytes + 255) & ~(size_t)255;
    return r;
  };
  float* out0 = (float*)alloc((size_t)N * 64 * 4);
  float* out1 = (float*)alloc((size_t)N * 64 * 4);
  float* out2 = (float*)alloc((size_t)N * 64 * 4);
  float* out3 = (float*)alloc((size_t)N * 64 * 4);
  float* feat = (float*)alloc((size_t)N * 64 * 4);
  float* el   = (float*)alloc((size_t)N * 4);
  float* er   = (float*)alloc((size_t)N * 4);
  int* counts  = (int*)alloc((size_t)N * 4);
  int* row_ptr = (int*)alloc((size_t)(N + 1) * 4);
  int* cursor  = (int*)alloc((size_t)N * 4);
  int* csr_src = (int*)alloc((size_t)E * 4);
  unsigned char* mask = (unsigned char*)alloc((size_t)E);
  int nb = (N + 1023) / 1024;
  int* bsum = (int*)alloc((size_t)nb * 4);
  int* bofs = (int*)alloc((size_t)nb * 4);
  float* wt = (float*)alloc((size_t)WT_TOT * 4);

  // --- prep: zero counts + transpose all weight matrices ---
  int prep_n = (N > WT_TOT) ? N : WT_TOT;
  k_prep<<<(prep_n + 255) / 256, 256, 0, stream>>>(W_embed, W_gat, W0, W1,
                                                   wt, counts, N);

  // --- CSR build (dst-sorted) ---
  k_hist<<<(E + 255) / 256, 256, 0, stream>>>(edst, counts, E);
  k_bsum<<<nb, 1024, 0, stream>>>(counts, bsum, N);
  k_bscan<<<1, 64, 0, stream>>>(bsum, bofs, row_ptr, nb, N);
  k_scan3<<<nb, 1024, 0, stream>>>(counts, bofs, row_ptr, cursor, N);
  k_scatter<<<(E + 255) / 256, 256, 0, stream>>>(esrc, edst, cursor, csr_src, E);

  // --- dense grid: 64 nodes per 256-thread block ---
  int dgb = (N + 63) / 64;

  // --- layer 0: fused embed + feat ---
  k_embed_feat<<<dgb, 256, 0, stream>>>(x, wt + WT_EMB, wt + WT_GAT,
                                        a_l, a_r, feat, el, er, N);
  float* outs[4] = {out0, out1, out2, out3};
  k_aggr<<<(N + 3) / 4, 256, 0, stream>>>(feat, el, er, row_ptr, csr_src, mask,
                                          1, 0, out0, N);

  // --- layers 1..3 ---
  for (int l = 1; l < 4; l++) {
    k_feat<<<dgb, 256, 0, stream>>>(outs[l - 1], wt + WT_GAT + (size_t)l * 4096,
                                    a_l + (size_t)l * 64, a_r + (size_t)l * 64,
                                    feat, el, er, N);
    k_aggr<<<(N + 3) / 4, 256, 0, stream>>>(feat, el, er, row_ptr, csr_src, mask,
                                            0, 1, outs[l], N);
  }

  // --- MLP head ---
  k_mlp<<<dgb, 256, 0, stream>>>(out0, out1, out2, out3, wt + WT_W0, b0,
                                 wt + WT_W1, b1, W2, b2, out, N);
}

// Round 11
// 529.486 us; speedup vs baseline: 1.8632x; 1.3967x over previous
//
#include <hip/hip_runtime.h>
#include <math.h>

// ---------------------------------------------------------------------------
// SNAT3: 4-layer GAT GNN. N=50000, E=800000, HID=64, fp32.
// R11: R7 inner-loop shape, but 512-thread blocks (8 waves x 8 features):
//   lane = node (64 nodes/block), wave wv owns features [8wv, 8wv+8).
//   R7's 32% occupancy was the GRID limit (782 blk x 4 waves / 256 CU = 12
//   waves/CU). 8 waves/block -> 24 waves/CU (76% cap) with the same grid.
//   K chunked by 16 (a[16] live max -- the no-spill codegen from R5/R10);
//   weights via wave-uniform s_load from transposed wt[f][k]; 8-feature rows
//   halve live SGPR weight buffers (R10's 64-SGPR single-buffering pathology).
// k_aggr / CSR build unchanged from R7.
// ---------------------------------------------------------------------------

#define WT_EMB 0
#define WT_GAT 8192
#define WT_W0  24576
#define WT_W1  40960
#define WT_TOT 45056

__global__ void k_prep(const float* __restrict__ We, const float* __restrict__ Wg,
                       const float* __restrict__ W0, const float* __restrict__ W1,
                       float* __restrict__ wt, int* __restrict__ counts, int N) {
  int i = blockIdx.x * 256 + threadIdx.x;
  if (i < N) counts[i] = 0;
  if (i < 8192) {                       // W_embed [128][64] -> [64f][128k]
    int k = i >> 6, f = i & 63;
    wt[WT_EMB + f * 128 + k] = We[i];
  } else if (i < 24576) {               // W_gat [4][64][64] -> [4][64f][64k]
    int j = i - 8192, l = j >> 12, r = j & 4095;
    int k = r >> 6, f = r & 63;
    wt[WT_GAT + l * 4096 + f * 64 + k] = Wg[j];
  } else if (i < 40960) {               // W0 [256][64] -> [64f][256k]
    int j = i - 24576, k = j >> 6, f = j & 63;
    wt[WT_W0 + f * 256 + k] = W0[j];
  } else if (i < WT_TOT) {              // W1 [64][64] -> [64f][64k]
    int j = i - 40960, k = j >> 6, f = j & 63;
    wt[WT_W1 + f * 64 + k] = W1[j];
  }
}

__global__ void k_hist(const int* __restrict__ dst, int* __restrict__ counts, int E) {
  int e = blockIdx.x * blockDim.x + threadIdx.x;
  if (e < E) atomicAdd(&counts[dst[e]], 1);
}

__global__ __launch_bounds__(1024) void k_bsum(const int* __restrict__ counts,
                                               int* __restrict__ bsum, int n) {
  __shared__ int wsum[16];
  int tid = threadIdx.x, lane = tid & 63, wid = tid >> 6;
  int i = blockIdx.x * 1024 + tid;
  int v = (i < n) ? counts[i] : 0;
  #pragma unroll
  for (int off = 32; off; off >>= 1) v += __shfl_xor(v, off, 64);
  if (lane == 0) wsum[wid] = v;
  __syncthreads();
  if (wid == 0) {
    int w = (lane < 16) ? wsum[lane] : 0;
    #pragma unroll
    for (int off = 8; off; off >>= 1) w += __shfl_xor(w, off, 64);
    if (lane == 0) bsum[blockIdx.x] = w;
  }
}

__global__ __launch_bounds__(64) void k_bscan(const int* __restrict__ bsum,
                                              int* __restrict__ bofs,
                                              int* __restrict__ row_ptr,
                                              int nb, int n) {
  int lane = threadIdx.x;
  int carry = 0;
  for (int base = 0; base < nb; base += 64) {
    int idx = base + lane;
    int orig = (idx < nb) ? bsum[idx] : 0;
    int inc = orig;
    #pragma unroll
    for (int off = 1; off < 64; off <<= 1) {
      int t = __shfl_up(inc, off, 64);
      if (lane >= off) inc += t;
    }
    if (idx < nb) bofs[idx] = carry + inc - orig;
    carry += __shfl(inc, 63, 64);
  }
  if (lane == 0) row_ptr[n] = carry;
}

__global__ __launch_bounds__(1024) void k_scan3(const int* __restrict__ counts,
                                                const int* __restrict__ bofs,
                                                int* __restrict__ row_ptr,
                                                int* __restrict__ cursor, int n) {
  __shared__ int wsum[16];
  int tid = threadIdx.x, lane = tid & 63, wid = tid >> 6;
  int i = blockIdx.x * 1024 + tid;
  int v = (i < n) ? counts[i] : 0;
  int inc = v;
  #pragma unroll
  for (int off = 1; off < 64; off <<= 1) {
    int t = __shfl_up(inc, off, 64);
    if (lane >= off) inc += t;
  }
  if (lane == 63) wsum[wid] = inc;
  __syncthreads();
  if (wid == 0 && lane < 16) {
    int orig = wsum[lane];
    int w = orig;
    #pragma unroll
    for (int off = 1; off < 16; off <<= 1) {
      int t = __shfl_up(w, off, 64);
      if (lane >= off) w += t;
    }
    wsum[lane] = w - orig;
  }
  __syncthreads();
  int excl = bofs[blockIdx.x] + wsum[wid] + inc - v;
  if (i < n) { row_ptr[i] = excl; cursor[i] = excl; }
}

__global__ void k_scatter(const int* __restrict__ src, const int* __restrict__ dst,
                          int* __restrict__ cursor, int* __restrict__ csr_src, int E) {
  int e = blockIdx.x * blockDim.x + threadIdx.x;
  if (e < E) {
    int pos = atomicAdd(&cursor[dst[e]], 1);
    csr_src[pos] = src[e];
  }
}

// ---- fused: h = tanh(x@We); feat = h@Wg0; el/er. 512thr: 8 waves x 8 f ----
__global__ __launch_bounds__(512) void k_embed_feat(
    const float* __restrict__ x, const float* __restrict__ wte,
    const float* __restrict__ wtg, const float* __restrict__ al,
    const float* __restrict__ ar, float* __restrict__ feat,
    float* __restrict__ el, float* __restrict__ er, int N) {
  __shared__ float sB[64 * 65];    // h exchange [node][f], pad65
  __shared__ float sE[16 * 64];    // el/er partials [2][8 waves][lane]
  int tid = threadIdx.x, lane = tid & 63, wv = tid >> 6;
  int n = blockIdx.x * 64 + lane;
  int nn = min(n, N - 1);
  int f0 = __builtin_amdgcn_readfirstlane(wv * 8);
  const float* xp = x + (size_t)nn * 128;
  float acc[8];
  #pragma unroll
  for (int f = 0; f < 8; f++) acc[f] = 0.f;
  for (int kc = 0; kc < 8; kc++) {           // K=128, chunks of 16
    float4 v0 = *(const float4*)(xp + kc * 16 + 0);
    float4 v1 = *(const float4*)(xp + kc * 16 + 4);
    float4 v2 = *(const float4*)(xp + kc * 16 + 8);
    float4 v3 = *(const float4*)(xp + kc * 16 + 12);
    float a[16] = {v0.x, v0.y, v0.z, v0.w, v1.x, v1.y, v1.z, v1.w,
                   v2.x, v2.y, v2.z, v2.w, v3.x, v3.y, v3.z, v3.w};
    #pragma unroll
    for (int f = 0; f < 8; f++) {
      const float* wr = wte + (f0 + f) * 128 + kc * 16;  // uniform -> s_load
      #pragma unroll
      for (int k = 0; k < 16; k++) acc[f] = fmaf(a[k], wr[k], acc[f]);
    }
  }
  #pragma unroll
  for (int f = 0; f < 8; f++) sB[lane * 65 + f0 + f] = tanhf(acc[f]);
  __syncthreads();
  float acc2[8];
  #pragma unroll
  for (int f = 0; f < 8; f++) acc2[f] = 0.f;
  for (int kc = 0; kc < 4; kc++) {           // h from LDS, chunks of 16
    float a[16];
    #pragma unroll
    for (int k = 0; k < 16; k++) a[k] = sB[lane * 65 + kc * 16 + k];
    #pragma unroll
    for (int f = 0; f < 8; f++) {
      const float* wr = wtg + (f0 + f) * 64 + kc * 16;   // uniform -> s_load
      #pragma unroll
      for (int k = 0; k < 16; k++) acc2[f] = fmaf(a[k], wr[k], acc2[f]);
    }
  }
  float rl = 0.f, rr = 0.f;
  #pragma unroll
  for (int f = 0; f < 8; f++) {
    rl = fmaf(acc2[f], al[f0 + f], rl);
    rr = fmaf(acc2[f], ar[f0 + f], rr);
  }
  sE[wv * 64 + lane] = rl;
  sE[512 + wv * 64 + lane] = rr;
  if (n < N) {                               // 8-feature slice store
    float* fp = feat + (size_t)n * 64 + f0;
    *(float4*)(fp + 0) = make_float4(acc2[0], acc2[1], acc2[2], acc2[3]);
    *(float4*)(fp + 4) = make_float4(acc2[4], acc2[5], acc2[6], acc2[7]);
  }
  __syncthreads();
  if (tid < 64) {
    int no = blockIdx.x * 64 + tid;
    if (no < N) {
      float sl = 0.f, sr = 0.f;
      #pragma unroll
      for (int w = 0; w < 8; w++) {
        sl += sE[w * 64 + tid];
        sr += sE[512 + w * 64 + tid];
      }
      el[no] = sl;
      er[no] = sr;
    }
  }
}

// ---- feat = hin @ Wg; el/er (layers 1..3). 512thr: 8 waves x 8 f ----
__global__ __launch_bounds__(512) void k_feat(const float* __restrict__ hin,
                                              const float* __restrict__ wt,
                                              const float* __restrict__ al,
                                              const float* __restrict__ ar,
                                              float* __restrict__ feat,
                                              float* __restrict__ el,
                                              float* __restrict__ er, int N) {
  __shared__ float sE[16 * 64];
  int tid = threadIdx.x, lane = tid & 63, wv = tid >> 6;
  int n = blockIdx.x * 64 + lane;
  int nn = min(n, N - 1);
  int f0 = __builtin_amdgcn_readfirstlane(wv * 8);
  const float* hp = hin + (size_t)nn * 64;
  float acc[8];
  #pragma unroll
  for (int f = 0; f < 8; f++) acc[f] = 0.f;
  for (int kc = 0; kc < 4; kc++) {           // K=64, chunks of 16
    float4 v0 = *(const float4*)(hp + kc * 16 + 0);
    float4 v1 = *(const float4*)(hp + kc * 16 + 4);
    float4 v2 = *(const float4*)(hp + kc * 16 + 8);
    float4 v3 = *(const float4*)(hp + kc * 16 + 12);
    float a[16] = {v0.x, v0.y, v0.z, v0.w, v1.x, v1.y, v1.z, v1.w,
                   v2.x, v2.y, v2.z, v2.w, v3.x, v3.y, v3.z, v3.w};
    #pragma unroll
    for (int f = 0; f < 8; f++) {
      const float* wr = wt + (f0 + f) * 64 + kc * 16;    // uniform -> s_load
      #pragma unroll
      for (int k = 0; k < 16; k++) acc[f] = fmaf(a[k], wr[k], acc[f]);
    }
  }
  float rl = 0.f, rr = 0.f;
  #pragma unroll
  for (int f = 0; f < 8; f++) {
    rl = fmaf(acc[f], al[f0 + f], rl);
    rr = fmaf(acc[f], ar[f0 + f], rr);
  }
  sE[wv * 64 + lane] = rl;
  sE[512 + wv * 64 + lane] = rr;
  if (n < N) {
    float* fp = feat + (size_t)n * 64 + f0;
    *(float4*)(fp + 0) = make_float4(acc[0], acc[1], acc[2], acc[3]);
    *(float4*)(fp + 4) = make_float4(acc[4], acc[5], acc[6], acc[7]);
  }
  __syncthreads();
  if (tid < 64) {
    int no = blockIdx.x * 64 + tid;
    if (no < N) {
      float sl = 0.f, sr = 0.f;
      #pragma unroll
      for (int w = 0; w < 8; w++) {
        sl += sE[w * 64 + tid];
        sr += sE[512 + w * 64 + tid];
      }
      el[no] = sl;
      er[no] = sr;
    }
  }
}

// ---- edge softmax + aggregate: one wave per dst node, lane = feature ----
__global__ __launch_bounds__(256) void k_aggr(const float* __restrict__ feat,
                                              const float* __restrict__ el,
                                              const float* __restrict__ er,
                                              const int* __restrict__ row_ptr,
                                              const int* __restrict__ csr_src,
                                              unsigned char* __restrict__ mask,
                                              int write_mask, int use_mask,
                                              float* __restrict__ hout, int N) {
  __shared__ __align__(16) int   su[4][64];
  __shared__ __align__(16) float spl[4][64];
  int wv = (int)((blockIdx.x * blockDim.x + threadIdx.x) >> 6);
  int wave = threadIdx.x >> 6, lane = threadIdx.x & 63;
  if (wv >= N) return;
  int beg = row_ptr[wv], end = row_ptr[wv + 1];
  int deg = end - beg;
  float erv = er[wv];
  float acc0 = 0.f, acc1 = 0.f, acc2 = 0.f, acc3 = 0.f;
  if (deg <= 64) {
    int k = beg + lane;
    bool have = (lane < deg);
    int u = have ? csr_src[k] : 0;
    float sc = -INFINITY;
    if (have) {
      float e0 = el[u] + erv;
      sc = (e0 >= 0.f) ? e0 : 0.2f * e0;
      if (use_mask && mask[k] == 0) sc = -1e9f;
    }
    float m = sc;
    #pragma unroll
    for (int off = 32; off; off >>= 1) m = fmaxf(m, __shfl_xor(m, off, 64));
    float pl = have ? expf(sc - m) : 0.f;
    float s = pl;
    #pragma unroll
    for (int off = 32; off; off >>= 1) s += __shfl_xor(s, off, 64);
    pl *= 1.0f / fmaxf(s, 1e-9f);
    if (write_mask && have) mask[k] = (pl >= 0.01f) ? 1 : 0;
    su[wave][lane] = u;
    spl[wave][lane] = pl;
    int dq = (deg + 3) >> 2;
    #pragma unroll 2
    for (int q = 0; q < dq; q++) {
      int4   uu = *(const int4*)&su[wave][q * 4];
      float4 pp = *(const float4*)&spl[wave][q * 4];
      acc0 = fmaf(pp.x, feat[(size_t)uu.x * 64 + lane], acc0);
      acc1 = fmaf(pp.y, feat[(size_t)uu.y * 64 + lane], acc1);
      acc2 = fmaf(pp.z, feat[(size_t)uu.z * 64 + lane], acc2);
      acc3 = fmaf(pp.w, feat[(size_t)uu.w * 64 + lane], acc3);
    }
  } else {
    float m = -INFINITY, s = 0.f;
    for (int base = beg; base < end; base += 64) {
      int k = base + lane;
      float sc = -INFINITY;
      if (k < end) {
        int u = csr_src[k];
        float e0 = el[u] + erv;
        sc = (e0 >= 0.f) ? e0 : 0.2f * e0;
        if (use_mask && mask[k] == 0) sc = -1e9f;
      }
      float cm = sc;
      #pragma unroll
      for (int off = 32; off; off >>= 1) cm = fmaxf(cm, __shfl_xor(cm, off, 64));
      float nm = fmaxf(m, cm);
      float t = (k < end) ? expf(sc - nm) : 0.f;
      #pragma unroll
      for (int off = 32; off; off >>= 1) t += __shfl_xor(t, off, 64);
      s = s * expf(m - nm) + t;
      m = nm;
    }
    float inv = 1.0f / fmaxf(s, 1e-9f);
    for (int base = beg; base < end; base += 64) {
      int k = base + lane;
      int u = 0;
      float pl = 0.f;
      if (k < end) {
        u = csr_src[k];
        float e0 = el[u] + erv;
        float sc = (e0 >= 0.f) ? e0 : 0.2f * e0;
        if (use_mask && mask[k] == 0) sc = -1e9f;
        pl = expf(sc - m) * inv;
        if (write_mask) mask[k] = (pl >= 0.01f) ? 1 : 0;
      }
      su[wave][lane] = u;
      spl[wave][lane] = pl;
      int cnt = min(64, end - base);
      int dq = (cnt + 3) >> 2;
      for (int q = 0; q < dq; q++) {
        int4   uu = *(const int4*)&su[wave][q * 4];
        float4 pp = *(const float4*)&spl[wave][q * 4];
        acc0 = fmaf(pp.x, feat[(size_t)uu.x * 64 + lane], acc0);
        acc1 = fmaf(pp.y, feat[(size_t)uu.y * 64 + lane], acc1);
        acc2 = fmaf(pp.z, feat[(size_t)uu.z * 64 + lane], acc2);
        acc3 = fmaf(pp.w, feat[(size_t)uu.w * 64 + lane], acc3);
      }
    }
  }
  float acc = (acc0 + acc1) + (acc2 + acc3);
  hout[(size_t)wv * 64 + lane] = (acc > 0.f) ? acc : expm1f(acc);
}

// ---- fused MLP head. 512thr: 8 waves x 8 features ----
__global__ __launch_bounds__(512) void k_mlp(const float* __restrict__ o0,
                                             const float* __restrict__ o1,
                                             const float* __restrict__ o2,
                                             const float* __restrict__ o3,
                                             const float* __restrict__ wt0,
                                             const float* __restrict__ b0,
                                             const float* __restrict__ wt1,
                                             const float* __restrict__ b1,
                                             const float* __restrict__ W2,
                                             const float* __restrict__ b2,
                                             float* __restrict__ out, int N) {
  __shared__ float sB[64 * 65];   // layer-0 output exchange
  __shared__ float sR[8 * 64];    // layer-2 partials
  int tid = threadIdx.x, lane = tid & 63, wv = tid >> 6;
  int n = blockIdx.x * 64 + lane;
  int nn = min(n, N - 1);
  int f0 = __builtin_amdgcn_readfirstlane(wv * 8);
  float acc[8];
  #pragma unroll
  for (int f = 0; f < 8; f++) acc[f] = b0[f0 + f];
  const float* segs[4] = {o0, o1, o2, o3};
  for (int sg = 0; sg < 4; sg++) {
    const float* sp = segs[sg] + (size_t)nn * 64;
    for (int kc = 0; kc < 4; kc++) {         // 16-k chunks, a[16] live max
      float4 v0 = *(const float4*)(sp + kc * 16 + 0);
      float4 v1 = *(const float4*)(sp + kc * 16 + 4);
      float4 v2 = *(const float4*)(sp + kc * 16 + 8);
      float4 v3 = *(const float4*)(sp + kc * 16 + 12);
      float a[16] = {v0.x, v0.y, v0.z, v0.w, v1.x, v1.y, v1.z, v1.w,
                     v2.x, v2.y, v2.z, v2.w, v3.x, v3.y, v3.z, v3.w};
      #pragma unroll
      for (int f = 0; f < 8; f++) {
        const float* wr = wt0 + (f0 + f) * 256 + sg * 64 + kc * 16;  // s_load
        #pragma unroll
        for (int k = 0; k < 16; k++) acc[f] = fmaf(a[k], wr[k], acc[f]);
      }
    }
  }
  #pragma unroll
  for (int f = 0; f < 8; f++)
    sB[lane * 65 + f0 + f] = (acc[f] > 0.f) ? acc[f] : 0.f;   // relu
  __syncthreads();
  float a1[8];
  #pragma unroll
  for (int f = 0; f < 8; f++) a1[f] = b1[f0 + f];
  for (int kc = 0; kc < 4; kc++) {           // layer-1 acts from LDS, chunked
    float a[16];
    #pragma unroll
    for (int k = 0; k < 16; k++) a[k] = sB[lane * 65 + kc * 16 + k];
    #pragma unroll
    for (int f = 0; f < 8; f++) {
      const float* wr = wt1 + (f0 + f) * 64 + kc * 16;     // uniform -> s_load
      #pragma unroll
      for (int k = 0; k < 16; k++) a1[f] = fmaf(a[k], wr[k], a1[f]);
    }
  }
  float rp = 0.f;
  #pragma unroll
  for (int f = 0; f < 8; f++) {
    float t = (a1[f] > 0.f) ? a1[f] : 0.f;
    rp = fmaf(t, W2[f0 + f], rp);
  }
  sR[wv * 64 + lane] = rp;
  __syncthreads();
  if (tid < 64) {
    int no = blockIdx.x * 64 + tid;
    if (no < N) {
      float o = b2[0];
      #pragma unroll
      for (int w = 0; w < 8; w++) o += sR[w * 64 + tid];
      out[no] = (o > 0.f) ? o : 0.f;
    }
  }
}

extern "C" void kernel_launch(void* const* d_in, const int* in_sizes, int n_in,
                              void* d_out, int out_size, void* d_ws, size_t ws_size,
                              hipStream_t stream) {
  const float* x       = (const float*)d_in[0];
  const int*   esrc    = (const int*)d_in[1];
  const int*   edst    = (const int*)d_in[2];
  const float* W_embed = (const float*)d_in[3];
  const float* W_gat   = (const float*)d_in[4];
  const float* a_l     = (const float*)d_in[5];
  const float* a_r     = (const float*)d_in[6];
  const float* W0      = (const float*)d_in[7];
  const float* b0      = (const float*)d_in[8];
  const float* W1      = (const float*)d_in[9];
  const float* b1      = (const float*)d_in[10];
  const float* W2      = (const float*)d_in[11];
  const float* b2      = (const float*)d_in[12];
  float* out = (float*)d_out;
  const int N = in_sizes[0] / 128;
  const int E = in_sizes[1];

  char* p = (char*)d_ws;
  auto alloc = [&](size_t bytes) -> char* {
    char* r = p;
    p += (bytes + 255) & ~(size_t)255;
    return r;
  };
  float* out0 = (float*)alloc((size_t)N * 64 * 4);
  float* out1 = (float*)alloc((size_t)N * 64 * 4);
  float* out2 = (float*)alloc((size_t)N * 64 * 4);
  float* out3 = (float*)alloc((size_t)N * 64 * 4);
  float* feat = (float*)alloc((size_t)N * 64 * 4);
  float* el   = (float*)alloc((size_t)N * 4);
  float* er   = (float*)alloc((size_t)N * 4);
  int* counts  = (int*)alloc((size_t)N * 4);
  int* row_ptr = (int*)alloc((size_t)(N + 1) * 4);
  int* cursor  = (int*)alloc((size_t)N * 4);
  int* csr_src = (int*)alloc((size_t)E * 4);
  unsigned char* mask = (unsigned char*)alloc((size_t)E);
  int nb = (N + 1023) / 1024;
  int* bsum = (int*)alloc((size_t)nb * 4);
  int* bofs = (int*)alloc((size_t)nb * 4);
  float* wt = (float*)alloc((size_t)WT_TOT * 4);

  // --- prep: zero counts + transpose all weight matrices ---
  int prep_n = (N > WT_TOT) ? N : WT_TOT;
  k_prep<<<(prep_n + 255) / 256, 256, 0, stream>>>(W_embed, W_gat, W0, W1,
                                                   wt, counts, N);

  // --- CSR build (dst-sorted) ---
  k_hist<<<(E + 255) / 256, 256, 0, stream>>>(edst, counts, E);
  k_bsum<<<nb, 1024, 0, stream>>>(counts, bsum, N);
  k_bscan<<<1, 64, 0, stream>>>(bsum, bofs, row_ptr, nb, N);
  k_scan3<<<nb, 1024, 0, stream>>>(counts, bofs, row_ptr, cursor, N);
  k_scatter<<<(E + 255) / 256, 256, 0, stream>>>(esrc, edst, cursor, csr_src, E);

  // --- dense grid: 64 nodes per 512-thread block ---
  int dgb = (N + 63) / 64;

  // --- layer 0: fused embed + feat ---
  k_embed_feat<<<dgb, 512, 0, stream>>>(x, wt + WT_EMB, wt + WT_GAT,
                                        a_l, a_r, feat, el, er, N);
  float* outs[4] = {out0, out1, out2, out3};
  k_aggr<<<(N + 3) / 4, 256, 0, stream>>>(feat, el, er, row_ptr, csr_src, mask,
                                          1, 0, out0, N);

  // --- layers 1..3 ---
  for (int l = 1; l < 4; l++) {
    k_feat<<<dgb, 512, 0, stream>>>(outs[l - 1], wt + WT_GAT + (size_t)l * 4096,
                                    a_l + (size_t)l * 64, a_r + (size_t)l * 64,
                                    feat, el, er, N);
    k_aggr<<<(N + 3) / 4, 256, 0, stream>>>(feat, el, er, row_ptr, csr_src, mask,
                                            0, 1, outs[l], N);
  }

  // --- MLP head ---
  k_mlp<<<dgb, 512, 0, stream>>>(out0, out1, out2, out3, wt + WT_W0, b0,
                                 wt + WT_W1, b1, W2, b2, out, N);
}

// Round 12
// 527.624 us; speedup vs baseline: 1.8698x; 1.0035x over previous
//
#include <hip/hip_runtime.h>
#include <math.h>

// ---------------------------------------------------------------------------
// SNAT3: 4-layer GAT GNN. N=50000, E=800000, HID=64, fp32.
// R12 = R11 + explicit double-buffered activation prefetch in dense kernels.
// R11 compiled k_mlp at 36 VGPR: single a[16] buffer -> s_waitcnt vmcnt(0)
// before every 16-FMA-per-f block -> ~350cyc exposed VMEM latency per chunk
// (VALUBusy 33%). Here next chunk's 4x float4 loads are issued BEFORE the
// current chunk's FMAs (separate named cur/nxt registers) so the wait becomes
// vmcnt(4) and latency overlaps FMA issue. Live set ~55-70 VGPR (no spill).
// Weights stay wave-uniform s_load from transposed wt (8 features per wave,
// 512-thread blocks = 8 waves x 64 nodes; occupancy cap 76%).
// k_aggr / CSR build unchanged.
// ---------------------------------------------------------------------------

#define WT_EMB 0
#define WT_GAT 8192
#define WT_W0  24576
#define WT_W1  40960
#define WT_TOT 45056

__global__ void k_prep(const float* __restrict__ We, const float* __restrict__ Wg,
                       const float* __restrict__ W0, const float* __restrict__ W1,
                       float* __restrict__ wt, int* __restrict__ counts, int N) {
  int i = blockIdx.x * 256 + threadIdx.x;
  if (i < N) counts[i] = 0;
  if (i < 8192) {                       // W_embed [128][64] -> [64f][128k]
    int k = i >> 6, f = i & 63;
    wt[WT_EMB + f * 128 + k] = We[i];
  } else if (i < 24576) {               // W_gat [4][64][64] -> [4][64f][64k]
    int j = i - 8192, l = j >> 12, r = j & 4095;
    int k = r >> 6, f = r & 63;
    wt[WT_GAT + l * 4096 + f * 64 + k] = Wg[j];
  } else if (i < 40960) {               // W0 [256][64] -> [64f][256k]
    int j = i - 24576, k = j >> 6, f = j & 63;
    wt[WT_W0 + f * 256 + k] = W0[j];
  } else if (i < WT_TOT) {              // W1 [64][64] -> [64f][64k]
    int j = i - 40960, k = j >> 6, f = j & 63;
    wt[WT_W1 + f * 64 + k] = W1[j];
  }
}

__global__ void k_hist(const int* __restrict__ dst, int* __restrict__ counts, int E) {
  int e = blockIdx.x * blockDim.x + threadIdx.x;
  if (e < E) atomicAdd(&counts[dst[e]], 1);
}

__global__ __launch_bounds__(1024) void k_bsum(const int* __restrict__ counts,
                                               int* __restrict__ bsum, int n) {
  __shared__ int wsum[16];
  int tid = threadIdx.x, lane = tid & 63, wid = tid >> 6;
  int i = blockIdx.x * 1024 + tid;
  int v = (i < n) ? counts[i] : 0;
  #pragma unroll
  for (int off = 32; off; off >>= 1) v += __shfl_xor(v, off, 64);
  if (lane == 0) wsum[wid] = v;
  __syncthreads();
  if (wid == 0) {
    int w = (lane < 16) ? wsum[lane] : 0;
    #pragma unroll
    for (int off = 8; off; off >>= 1) w += __shfl_xor(w, off, 64);
    if (lane == 0) bsum[blockIdx.x] = w;
  }
}

__global__ __launch_bounds__(64) void k_bscan(const int* __restrict__ bsum,
                                              int* __restrict__ bofs,
                                              int* __restrict__ row_ptr,
                                              int nb, int n) {
  int lane = threadIdx.x;
  int carry = 0;
  for (int base = 0; base < nb; base += 64) {
    int idx = base + lane;
    int orig = (idx < nb) ? bsum[idx] : 0;
    int inc = orig;
    #pragma unroll
    for (int off = 1; off < 64; off <<= 1) {
      int t = __shfl_up(inc, off, 64);
      if (lane >= off) inc += t;
    }
    if (idx < nb) bofs[idx] = carry + inc - orig;
    carry += __shfl(inc, 63, 64);
  }
  if (lane == 0) row_ptr[n] = carry;
}

__global__ __launch_bounds__(1024) void k_scan3(const int* __restrict__ counts,
                                                const int* __restrict__ bofs,
                                                int* __restrict__ row_ptr,
                                                int* __restrict__ cursor, int n) {
  __shared__ int wsum[16];
  int tid = threadIdx.x, lane = tid & 63, wid = tid >> 6;
  int i = blockIdx.x * 1024 + tid;
  int v = (i < n) ? counts[i] : 0;
  int inc = v;
  #pragma unroll
  for (int off = 1; off < 64; off <<= 1) {
    int t = __shfl_up(inc, off, 64);
    if (lane >= off) inc += t;
  }
  if (lane == 63) wsum[wid] = inc;
  __syncthreads();
  if (wid == 0 && lane < 16) {
    int orig = wsum[lane];
    int w = orig;
    #pragma unroll
    for (int off = 1; off < 16; off <<= 1) {
      int t = __shfl_up(w, off, 64);
      if (lane >= off) w += t;
    }
    wsum[lane] = w - orig;
  }
  __syncthreads();
  int excl = bofs[blockIdx.x] + wsum[wid] + inc - v;
  if (i < n) { row_ptr[i] = excl; cursor[i] = excl; }
}

__global__ void k_scatter(const int* __restrict__ src, const int* __restrict__ dst,
                          int* __restrict__ cursor, int* __restrict__ csr_src, int E) {
  int e = blockIdx.x * blockDim.x + threadIdx.x;
  if (e < E) {
    int pos = atomicAdd(&cursor[dst[e]], 1);
    csr_src[pos] = src[e];
  }
}

// ---- fused: h = tanh(x@We); feat = h@Wg0; el/er. 512thr: 8 waves x 8 f ----
__global__ __launch_bounds__(512) void k_embed_feat(
    const float* __restrict__ x, const float* __restrict__ wte,
    const float* __restrict__ wtg, const float* __restrict__ al,
    const float* __restrict__ ar, float* __restrict__ feat,
    float* __restrict__ el, float* __restrict__ er, int N) {
  __shared__ float sB[64 * 65];    // h exchange [node][f], pad65
  __shared__ float sE[16 * 64];    // el/er partials [2][8 waves][lane]
  int tid = threadIdx.x, lane = tid & 63, wv = tid >> 6;
  int n = blockIdx.x * 64 + lane;
  int nn = min(n, N - 1);
  int f0 = __builtin_amdgcn_readfirstlane(wv * 8);
  const float* xp = x + (size_t)nn * 128;
  float acc[8];
  #pragma unroll
  for (int f = 0; f < 8; f++) acc[f] = 0.f;
  // double-buffered: load chunk kc+1 before FMAs of chunk kc
  float4 c0 = *(const float4*)(xp + 0), c1 = *(const float4*)(xp + 4);
  float4 c2 = *(const float4*)(xp + 8), c3 = *(const float4*)(xp + 12);
  for (int kc = 0; kc < 8; kc++) {
    float4 n0, n1, n2, n3;
    if (kc < 7) {
      const float* g = xp + (kc + 1) * 16;
      n0 = *(const float4*)(g + 0); n1 = *(const float4*)(g + 4);
      n2 = *(const float4*)(g + 8); n3 = *(const float4*)(g + 12);
    }
    float a[16] = {c0.x, c0.y, c0.z, c0.w, c1.x, c1.y, c1.z, c1.w,
                   c2.x, c2.y, c2.z, c2.w, c3.x, c3.y, c3.z, c3.w};
    #pragma unroll
    for (int f = 0; f < 8; f++) {
      const float* wr = wte + (f0 + f) * 128 + kc * 16;  // uniform -> s_load
      #pragma unroll
      for (int k = 0; k < 16; k++) acc[f] = fmaf(a[k], wr[k], acc[f]);
    }
    if (kc < 7) { c0 = n0; c1 = n1; c2 = n2; c3 = n3; }
  }
  #pragma unroll
  for (int f = 0; f < 8; f++) sB[lane * 65 + f0 + f] = tanhf(acc[f]);
  __syncthreads();
  float acc2[8];
  #pragma unroll
  for (int f = 0; f < 8; f++) acc2[f] = 0.f;
  for (int kc = 0; kc < 4; kc++) {           // h from LDS, chunks of 16
    float a[16];
    #pragma unroll
    for (int k = 0; k < 16; k++) a[k] = sB[lane * 65 + kc * 16 + k];
    #pragma unroll
    for (int f = 0; f < 8; f++) {
      const float* wr = wtg + (f0 + f) * 64 + kc * 16;   // uniform -> s_load
      #pragma unroll
      for (int k = 0; k < 16; k++) acc2[f] = fmaf(a[k], wr[k], acc2[f]);
    }
  }
  float rl = 0.f, rr = 0.f;
  #pragma unroll
  for (int f = 0; f < 8; f++) {
    rl = fmaf(acc2[f], al[f0 + f], rl);
    rr = fmaf(acc2[f], ar[f0 + f], rr);
  }
  sE[wv * 64 + lane] = rl;
  sE[512 + wv * 64 + lane] = rr;
  if (n < N) {                               // 8-feature slice store
    float* fp = feat + (size_t)n * 64 + f0;
    *(float4*)(fp + 0) = make_float4(acc2[0], acc2[1], acc2[2], acc2[3]);
    *(float4*)(fp + 4) = make_float4(acc2[4], acc2[5], acc2[6], acc2[7]);
  }
  __syncthreads();
  if (tid < 64) {
    int no = blockIdx.x * 64 + tid;
    if (no < N) {
      float sl = 0.f, sr = 0.f;
      #pragma unroll
      for (int w = 0; w < 8; w++) {
        sl += sE[w * 64 + tid];
        sr += sE[512 + w * 64 + tid];
      }
      el[no] = sl;
      er[no] = sr;
    }
  }
}

// ---- feat = hin @ Wg; el/er (layers 1..3). 512thr: 8 waves x 8 f ----
__global__ __launch_bounds__(512) void k_feat(const float* __restrict__ hin,
                                              const float* __restrict__ wt,
                                              const float* __restrict__ al,
                                              const float* __restrict__ ar,
                                              float* __restrict__ feat,
                                              float* __restrict__ el,
                                              float* __restrict__ er, int N) {
  __shared__ float sE[16 * 64];
  int tid = threadIdx.x, lane = tid & 63, wv = tid >> 6;
  int n = blockIdx.x * 64 + lane;
  int nn = min(n, N - 1);
  int f0 = __builtin_amdgcn_readfirstlane(wv * 8);
  const float* hp = hin + (size_t)nn * 64;
  float acc[8];
  #pragma unroll
  for (int f = 0; f < 8; f++) acc[f] = 0.f;
  float4 c0 = *(const float4*)(hp + 0), c1 = *(const float4*)(hp + 4);
  float4 c2 = *(const float4*)(hp + 8), c3 = *(const float4*)(hp + 12);
  for (int kc = 0; kc < 4; kc++) {
    float4 n0, n1, n2, n3;
    if (kc < 3) {
      const float* g = hp + (kc + 1) * 16;
      n0 = *(const float4*)(g + 0); n1 = *(const float4*)(g + 4);
      n2 = *(const float4*)(g + 8); n3 = *(const float4*)(g + 12);
    }
    float a[16] = {c0.x, c0.y, c0.z, c0.w, c1.x, c1.y, c1.z, c1.w,
                   c2.x, c2.y, c2.z, c2.w, c3.x, c3.y, c3.z, c3.w};
    #pragma unroll
    for (int f = 0; f < 8; f++) {
      const float* wr = wt + (f0 + f) * 64 + kc * 16;    // uniform -> s_load
      #pragma unroll
      for (int k = 0; k < 16; k++) acc[f] = fmaf(a[k], wr[k], acc[f]);
    }
    if (kc < 3) { c0 = n0; c1 = n1; c2 = n2; c3 = n3; }
  }
  float rl = 0.f, rr = 0.f;
  #pragma unroll
  for (int f = 0; f < 8; f++) {
    rl = fmaf(acc[f], al[f0 + f], rl);
    rr = fmaf(acc[f], ar[f0 + f], rr);
  }
  sE[wv * 64 + lane] = rl;
  sE[512 + wv * 64 + lane] = rr;
  if (n < N) {
    float* fp = feat + (size_t)n * 64 + f0;
    *(float4*)(fp + 0) = make_float4(acc[0], acc[1], acc[2], acc[3]);
    *(float4*)(fp + 4) = make_float4(acc[4], acc[5], acc[6], acc[7]);
  }
  __syncthreads();
  if (tid < 64) {
    int no = blockIdx.x * 64 + tid;
    if (no < N) {
      float sl = 0.f, sr = 0.f;
      #pragma unroll
      for (int w = 0; w < 8; w++) {
        sl += sE[w * 64 + tid];
        sr += sE[512 + w * 64 + tid];
      }
      el[no] = sl;
      er[no] = sr;
    }
  }
}

// ---- edge softmax + aggregate: one wave per dst node, lane = feature ----
__global__ __launch_bounds__(256) void k_aggr(const float* __restrict__ feat,
                                              const float* __restrict__ el,
                                              const float* __restrict__ er,
                                              const int* __restrict__ row_ptr,
                                              const int* __restrict__ csr_src,
                                              unsigned char* __restrict__ mask,
                                              int write_mask, int use_mask,
                                              float* __restrict__ hout, int N) {
  __shared__ __align__(16) int   su[4][64];
  __shared__ __align__(16) float spl[4][64];
  int wv = (int)((blockIdx.x * blockDim.x + threadIdx.x) >> 6);
  int wave = threadIdx.x >> 6, lane = threadIdx.x & 63;
  if (wv >= N) return;
  int beg = row_ptr[wv], end = row_ptr[wv + 1];
  int deg = end - beg;
  float erv = er[wv];
  float acc0 = 0.f, acc1 = 0.f, acc2 = 0.f, acc3 = 0.f;
  if (deg <= 64) {
    int k = beg + lane;
    bool have = (lane < deg);
    int u = have ? csr_src[k] : 0;
    float sc = -INFINITY;
    if (have) {
      float e0 = el[u] + erv;
      sc = (e0 >= 0.f) ? e0 : 0.2f * e0;
      if (use_mask && mask[k] == 0) sc = -1e9f;
    }
    float m = sc;
    #pragma unroll
    for (int off = 32; off; off >>= 1) m = fmaxf(m, __shfl_xor(m, off, 64));
    float pl = have ? expf(sc - m) : 0.f;
    float s = pl;
    #pragma unroll
    for (int off = 32; off; off >>= 1) s += __shfl_xor(s, off, 64);
    pl *= 1.0f / fmaxf(s, 1e-9f);
    if (write_mask && have) mask[k] = (pl >= 0.01f) ? 1 : 0;
    su[wave][lane] = u;
    spl[wave][lane] = pl;
    int dq = (deg + 3) >> 2;
    #pragma unroll 2
    for (int q = 0; q < dq; q++) {
      int4   uu = *(const int4*)&su[wave][q * 4];
      float4 pp = *(const float4*)&spl[wave][q * 4];
      acc0 = fmaf(pp.x, feat[(size_t)uu.x * 64 + lane], acc0);
      acc1 = fmaf(pp.y, feat[(size_t)uu.y * 64 + lane], acc1);
      acc2 = fmaf(pp.z, feat[(size_t)uu.z * 64 + lane], acc2);
      acc3 = fmaf(pp.w, feat[(size_t)uu.w * 64 + lane], acc3);
    }
  } else {
    float m = -INFINITY, s = 0.f;
    for (int base = beg; base < end; base += 64) {
      int k = base + lane;
      float sc = -INFINITY;
      if (k < end) {
        int u = csr_src[k];
        float e0 = el[u] + erv;
        sc = (e0 >= 0.f) ? e0 : 0.2f * e0;
        if (use_mask && mask[k] == 0) sc = -1e9f;
      }
      float cm = sc;
      #pragma unroll
      for (int off = 32; off; off >>= 1) cm = fmaxf(cm, __shfl_xor(cm, off, 64));
      float nm = fmaxf(m, cm);
      float t = (k < end) ? expf(sc - nm) : 0.f;
      #pragma unroll
      for (int off = 32; off; off >>= 1) t += __shfl_xor(t, off, 64);
      s = s * expf(m - nm) + t;
      m = nm;
    }
    float inv = 1.0f / fmaxf(s, 1e-9f);
    for (int base = beg; base < end; base += 64) {
      int k = base + lane;
      int u = 0;
      float pl = 0.f;
      if (k < end) {
        u = csr_src[k];
        float e0 = el[u] + erv;
        float sc = (e0 >= 0.f) ? e0 : 0.2f * e0;
        if (use_mask && mask[k] == 0) sc = -1e9f;
        pl = expf(sc - m) * inv;
        if (write_mask) mask[k] = (pl >= 0.01f) ? 1 : 0;
      }
      su[wave][lane] = u;
      spl[wave][lane] = pl;
      int cnt = min(64, end - base);
      int dq = (cnt + 3) >> 2;
      for (int q = 0; q < dq; q++) {
        int4   uu = *(const int4*)&su[wave][q * 4];
        float4 pp = *(const float4*)&spl[wave][q * 4];
        acc0 = fmaf(pp.x, feat[(size_t)uu.x * 64 + lane], acc0);
        acc1 = fmaf(pp.y, feat[(size_t)uu.y * 64 + lane], acc1);
        acc2 = fmaf(pp.z, feat[(size_t)uu.z * 64 + lane], acc2);
        acc3 = fmaf(pp.w, feat[(size_t)uu.w * 64 + lane], acc3);
      }
    }
  }
  float acc = (acc0 + acc1) + (acc2 + acc3);
  hout[(size_t)wv * 64 + lane] = (acc > 0.f) ? acc : expm1f(acc);
}

// ---- fused MLP head. 512thr: 8 waves x 8 features; pipelined chunks ----
__global__ __launch_bounds__(512) void k_mlp(const float* __restrict__ o0,
                                             const float* __restrict__ o1,
                                             const float* __restrict__ o2,
                                             const float* __restrict__ o3,
                                             const float* __restrict__ wt0,
                                             const float* __restrict__ b0,
                                             const float* __restrict__ wt1,
                                             const float* __restrict__ b1,
                                             const float* __restrict__ W2,
                                             const float* __restrict__ b2,
                                             float* __restrict__ out, int N) {
  __shared__ float sB[64 * 65];   // layer-0 output exchange
  __shared__ float sR[8 * 64];    // layer-2 partials
  int tid = threadIdx.x, lane = tid & 63, wv = tid >> 6;
  int n = blockIdx.x * 64 + lane;
  int nn = min(n, N - 1);
  int f0 = __builtin_amdgcn_readfirstlane(wv * 8);
  float acc[8];
  #pragma unroll
  for (int f = 0; f < 8; f++) acc[f] = b0[f0 + f];
  const float* segs[4] = {o0 + (size_t)nn * 64, o1 + (size_t)nn * 64,
                          o2 + (size_t)nn * 64, o3 + (size_t)nn * 64};
  // 16 linear chunks (sg = t>>2, kc = t&3), double-buffered
  const float* g0 = segs[0];
  float4 c0 = *(const float4*)(g0 + 0), c1 = *(const float4*)(g0 + 4);
  float4 c2 = *(const float4*)(g0 + 8), c3 = *(const float4*)(g0 + 12);
  for (int t = 0; t < 16; t++) {
    float4 n0, n1, n2, n3;
    if (t < 15) {
      const float* g = segs[(t + 1) >> 2] + ((t + 1) & 3) * 16;
      n0 = *(const float4*)(g + 0); n1 = *(const float4*)(g + 4);
      n2 = *(const float4*)(g + 8); n3 = *(const float4*)(g + 12);
    }
    float a[16] = {c0.x, c0.y, c0.z, c0.w, c1.x, c1.y, c1.z, c1.w,
                   c2.x, c2.y, c2.z, c2.w, c3.x, c3.y, c3.z, c3.w};
    #pragma unroll
    for (int f = 0; f < 8; f++) {
      const float* wr = wt0 + (f0 + f) * 256 + t * 16;   // uniform -> s_load
      #pragma unroll
      for (int k = 0; k < 16; k++) acc[f] = fmaf(a[k], wr[k], acc[f]);
    }
    if (t < 15) { c0 = n0; c1 = n1; c2 = n2; c3 = n3; }
  }
  #pragma unroll
  for (int f = 0; f < 8; f++)
    sB[lane * 65 + f0 + f] = (acc[f] > 0.f) ? acc[f] : 0.f;   // relu
  __syncthreads();
  float a1[8];
  #pragma unroll
  for (int f = 0; f < 8; f++) a1[f] = b1[f0 + f];
  for (int kc = 0; kc < 4; kc++) {           // layer-1 acts from LDS, chunked
    float a[16];
    #pragma unroll
    for (int k = 0; k < 16; k++) a[k] = sB[lane * 65 + kc * 16 + k];
    #pragma unroll
    for (int f = 0; f < 8; f++) {
      const float* wr = wt1 + (f0 + f) * 64 + kc * 16;   // uniform -> s_load
      #pragma unroll
      for (int k = 0; k < 16; k++) a1[f] = fmaf(a[k], wr[k], a1[f]);
    }
  }
  float rp = 0.f;
  #pragma unroll
  for (int f = 0; f < 8; f++) {
    float t = (a1[f] > 0.f) ? a1[f] : 0.f;
    rp = fmaf(t, W2[f0 + f], rp);
  }
  sR[wv * 64 + lane] = rp;
  __syncthreads();
  if (tid < 64) {
    int no = blockIdx.x * 64 + tid;
    if (no < N) {
      float o = b2[0];
      #pragma unroll
      for (int w = 0; w < 8; w++) o += sR[w * 64 + tid];
      out[no] = (o > 0.f) ? o : 0.f;
    }
  }
}

extern "C" void kernel_launch(void* const* d_in, const int* in_sizes, int n_in,
                              void* d_out, int out_size, void* d_ws, size_t ws_size,
                              hipStream_t stream) {
  const float* x       = (const float*)d_in[0];
  const int*   esrc    = (const int*)d_in[1];
  const int*   edst    = (const int*)d_in[2];
  const float* W_embed = (const float*)d_in[3];
  const float* W_gat   = (const float*)d_in[4];
  const float* a_l     = (const float*)d_in[5];
  const float* a_r     = (const float*)d_in[6];
  const float* W0      = (const float*)d_in[7];
  const float* b0      = (const float*)d_in[8];
  const float* W1      = (const float*)d_in[9];
  const float* b1      = (const float*)d_in[10];
  const float* W2      = (const float*)d_in[11];
  const float* b2      = (const float*)d_in[12];
  float* out = (float*)d_out;
  const int N = in_sizes[0] / 128;
  const int E = in_sizes[1];

  char* p = (char*)d_ws;
  auto alloc = [&](size_t bytes) -> char* {
    char* r = p;
    p += (bytes + 255) & ~(size_t)255;
    return r;
  };
  float* out0 = (float*)alloc((size_t)N * 64 * 4);
  float* out1 = (float*)alloc((size_t)N * 64 * 4);
  float* out2 = (float*)alloc((size_t)N * 64 * 4);
  float* out3 = (float*)alloc((size_t)N * 64 * 4);
  float* feat = (float*)alloc((size_t)N * 64 * 4);
  float* el   = (float*)alloc((size_t)N * 4);
  float* er   = (float*)alloc((size_t)N * 4);
  int* counts  = (int*)alloc((size_t)N * 4);
  int* row_ptr = (int*)alloc((size_t)(N + 1) * 4);
  int* cursor  = (int*)alloc((size_t)N * 4);
  int* csr_src = (int*)alloc((size_t)E * 4);
  unsigned char* mask = (unsigned char*)alloc((size_t)E);
  int nb = (N + 1023) / 1024;
  int* bsum = (int*)alloc((size_t)nb * 4);
  int* bofs = (int*)alloc((size_t)nb * 4);
  float* wt = (float*)alloc((size_t)WT_TOT * 4);

  // --- prep: zero counts + transpose all weight matrices ---
  int prep_n = (N > WT_TOT) ? N : WT_TOT;
  k_prep<<<(prep_n + 255) / 256, 256, 0, stream>>>(W_embed, W_gat, W0, W1,
                                                   wt, counts, N);

  // --- CSR build (dst-sorted) ---
  k_hist<<<(E + 255) / 256, 256, 0, stream>>>(edst, counts, E);
  k_bsum<<<nb, 1024, 0, stream>>>(counts, bsum, N);
  k_bscan<<<1, 64, 0, stream>>>(bsum, bofs, row_ptr, nb, N);
  k_scan3<<<nb, 1024, 0, stream>>>(counts, bofs, row_ptr, cursor, N);
  k_scatter<<<(E + 255) / 256, 256, 0, stream>>>(esrc, edst, cursor, csr_src, E);

  // --- dense grid: 64 nodes per 512-thread block ---
  int dgb = (N + 63) / 64;

  // --- layer 0: fused embed + feat ---
  k_embed_feat<<<dgb, 512, 0, stream>>>(x, wt + WT_EMB, wt + WT_GAT,
                                        a_l, a_r, feat, el, er, N);
  float* outs[4] = {out0, out1, out2, out3};
  k_aggr<<<(N + 3) / 4, 256, 0, stream>>>(feat, el, er, row_ptr, csr_src, mask,
                                          1, 0, out0, N);

  // --- layers 1..3 ---
  for (int l = 1; l < 4; l++) {
    k_feat<<<dgb, 512, 0, stream>>>(outs[l - 1], wt + WT_GAT + (size_t)l * 4096,
                                    a_l + (size_t)l * 64, a_r + (size_t)l * 64,
                                    feat, el, er, N);
    k_aggr<<<(N + 3) / 4, 256, 0, stream>>>(feat, el, er, row_ptr, csr_src, mask,
                                            0, 1, outs[l], N);
  }

  // --- MLP head ---
  k_mlp<<<dgb, 512, 0, stream>>>(out0, out1, out2, out3, wt + WT_W0, b0,
                                 wt + WT_W1, b1, W2, b2, out, N);
}